// Round 3
// baseline (134.184 us; speedup 1.0000x reference)
//
#include <hip/hip_runtime.h>
#include <hip/hip_bf16.h>

// SoftModule fused forward, MI355X gfx950 — v3.
// All inputs f32 (per reference), output f32. 4 waves/WG, 16 rows/wave,
// wave-private LDS (no barriers). MFMA v_mfma_f32_16x16x16_f16 everywhere;
// weights pre-converted/transposed to f16 [N][K] in d_ws.

using f32x4 = __attribute__((ext_vector_type(4))) float;
using h16x4 = __attribute__((ext_vector_type(4))) _Float16;

#define MFMA16(a, b, c) __builtin_amdgcn_mfma_f32_16x16x16f16((a), (b), (c), 0, 0, 0)

__device__ __forceinline__ short h_bits(float f) {  // f32 -> f16 bits
  _Float16 h = (_Float16)f;
  return __builtin_bit_cast(short, h);
}

// ---------------- weight convert + transpose to f16 [N][K] ------------------
// wsh (f16) element offsets:
//   Ws1T [64][512] @0       Ws2T [64][64] @32768   WtT  [64][128] @36864
//   Wa0T [16][64]  @45056   Wa1T [16][64] @46080   Wc0T [64][16]  @47104
//   We0T [4][32][64] @48128 We1T [4][32][32] @56320 We2T [4][32][32] @60416
// biases kept f32 (672 floats) in biasf.
__global__ void sm_convert_v3(
    const float* __restrict__ Ws1, const float* __restrict__ Ws2, const float* __restrict__ Wt,
    const float* __restrict__ Wa0, const float* __restrict__ Wa1, const float* __restrict__ Wc0,
    const float* __restrict__ We0, const float* __restrict__ We1, const float* __restrict__ We2,
    const float* __restrict__ bs1, const float* __restrict__ bs2, const float* __restrict__ bt,
    const float* __restrict__ ba0, const float* __restrict__ ba1, const float* __restrict__ bc0,
    const float* __restrict__ be0, const float* __restrict__ be1, const float* __restrict__ be2,
    short* __restrict__ wsh, float* __restrict__ biasf) {
  int d = blockIdx.x * 256 + threadIdx.x;
  if (d < 64512) {
    float v;
    if      (d < 32768) { int o = d >> 9, k = d & 511;                 v = Ws1[k * 64 + o]; }
    else if (d < 36864) { int r = d - 32768, o = r >> 6, k = r & 63;   v = Ws2[k * 64 + o]; }
    else if (d < 45056) { int r = d - 36864, o = r >> 7, k = r & 127;  v = Wt[k * 64 + o]; }
    else if (d < 46080) { int r = d - 45056, o = r >> 6, k = r & 63;   v = Wa0[k * 16 + o]; }
    else if (d < 47104) { int r = d - 46080, o = r >> 6, k = r & 63;   v = Wa1[k * 16 + o]; }
    else if (d < 48128) { int r = d - 47104, o = r >> 4, k = r & 15;   v = Wc0[k * 64 + o]; }
    else if (d < 56320) { int r = d - 48128, n = r >> 11, o = (r >> 6) & 31, i = r & 63; v = We0[n * 2048 + i * 32 + o]; }
    else if (d < 60416) { int r = d - 56320, n = r >> 10, o = (r >> 5) & 31, i = r & 31; v = We1[n * 1024 + i * 32 + o]; }
    else                { int r = d - 60416, n = r >> 10, o = (r >> 5) & 31, i = r & 31; v = We2[n * 1024 + i * 32 + o]; }
    wsh[d] = h_bits(v);
  } else if (d < 65184) {
    int r = d - 64512;
    float v;
    if      (r < 64)  v = bs1[r];
    else if (r < 128) v = bs2[r - 64];
    else if (r < 192) v = bt[r - 128];
    else if (r < 208) v = ba0[r - 192];
    else if (r < 224) v = ba1[r - 208];
    else if (r < 288) v = bc0[r - 224];
    else if (r < 416) v = be0[r - 288];
    else if (r < 544) v = be1[r - 416];
    else              v = be2[r - 544];
    biasf[r] = v;
  }
}

// ---------------- fused forward ---------------------------------------------
__global__ __launch_bounds__(256) void sm_fused_v3(
    const float* __restrict__ obs, const float* __restrict__ task,
    const short* __restrict__ wsh, const float* __restrict__ biasf,
    float* __restrict__ out) {
  const int tid  = threadIdx.x;
  const int wave = tid >> 6;
  const int lane = tid & 63;
  const int q    = lane >> 4;   // k-group (A/B) / row-reg group (C/D)
  const int p    = lane & 15;   // row (A) / col (B, C/D)
  const int lrow = wave * 16;
  const int rowblk = blockIdx.x * 64 + lrow;

  __shared__ __align__(16) char lds[64 * 144 + 64 * 48 + 4 * 64 * 80]; // 32768 B
  char* x_lds = lds;                        // [64 rows] stride 144B : 64 f16 cols
  char* a_lds = lds + 64 * 144;             // [64 rows] stride 48B  : 16 f16 cols
  char* p_lds = lds + 64 * 144 + 64 * 48;   // [4][64 rows] stride 80B: 32 f16 cols

  const short* Ws1T = wsh;
  const short* Ws2T = wsh + 32768;
  const short* WtT  = wsh + 36864;
  const short* Wa0T = wsh + 45056;
  const short* Wa1T = wsh + 46080;
  const short* Wc0T = wsh + 47104;
  const short* We0T = wsh + 48128;
  const short* We1T = wsh + 56320;
  const short* We2T = wsh + 60416;
  const float* bs1 = biasf;        const float* bs2 = biasf + 64;
  const float* bt  = biasf + 128;  const float* ba0 = biasf + 192;
  const float* ba1 = biasf + 208;  const float* bc0 = biasf + 224;
  const float* be0 = biasf + 288;  const float* be1 = biasf + 416;
  const float* be2 = biasf + 544;

  const f32x4 z4 = {0.f, 0.f, 0.f, 0.f};

  // A-fragment: 4 f16 from f32 global at [row][k0..k0+3]
  auto loadA = [&](const float* base, int rowlen, int row, int k0) -> h16x4 {
    float4 v = *(const float4*)(base + (size_t)row * rowlen + k0);
    h16x4 a;
    a[0] = (_Float16)v.x; a[1] = (_Float16)v.y;
    a[2] = (_Float16)v.z; a[3] = (_Float16)v.w;
    return a;
  };
  auto stx  = [&](int row, int col, float v) { *(short*)(x_lds + row * 144 + col * 2) = h_bits(v); };
  auto ldx4 = [&](int row, int k0) -> h16x4 { return *(const h16x4*)(x_lds + row * 144 + k0 * 2); };
  auto ldb  = [&](const short* W, int off) -> h16x4 { return *(const h16x4*)(W + off); };

  // ---- S1: X1 = relu(obs @ Ws1 + bs1), K=512 (32 K-blocks of 16) ----
  f32x4 accX[4] = {z4, z4, z4, z4};
  for (int kb = 0; kb < 32; ++kb) {
    h16x4 a = loadA(obs, 512, rowblk + p, kb * 16 + q * 4);
#pragma unroll
    for (int nt = 0; nt < 4; ++nt)
      accX[nt] = MFMA16(a, ldb(Ws1T, (nt * 16 + p) * 512 + kb * 16 + q * 4), accX[nt]);
  }
#pragma unroll
  for (int nt = 0; nt < 4; ++nt) {
    float bias = bs1[nt * 16 + p];
#pragma unroll
    for (int r = 0; r < 4; ++r)
      stx(lrow + 4 * q + r, nt * 16 + p, fmaxf(accX[nt][r] + bias, 0.f));
  }

  // ---- S2: s = relu(X1 @ Ws2 + bs2), K=64 ----
  f32x4 accS[4] = {z4, z4, z4, z4};
#pragma unroll
  for (int kb = 0; kb < 4; ++kb) {
    h16x4 a = ldx4(lrow + p, kb * 16 + q * 4);
#pragma unroll
    for (int nt = 0; nt < 4; ++nt)
      accS[nt] = MFMA16(a, ldb(Ws2T, (nt * 16 + p) * 64 + kb * 16 + q * 4), accS[nt]);
  }
  float sf[4][4];
#pragma unroll
  for (int nt = 0; nt < 4; ++nt) {
    float bias = bs2[nt * 16 + p];
#pragma unroll
    for (int r = 0; r < 4; ++r) sf[nt][r] = fmaxf(accS[nt][r] + bias, 0.f);
  }
#pragma unroll
  for (int nt = 0; nt < 4; ++nt)
#pragma unroll
    for (int r = 0; r < 4; ++r) stx(lrow + 4 * q + r, nt * 16 + p, sf[nt][r]);

  // ---- T: t = relu(task @ Wt + bt), K=128; r0 = s*t ----
  f32x4 accT[4] = {z4, z4, z4, z4};
  for (int kb = 0; kb < 8; ++kb) {
    h16x4 a = loadA(task, 128, rowblk + p, kb * 16 + q * 4);
#pragma unroll
    for (int nt = 0; nt < 4; ++nt)
      accT[nt] = MFMA16(a, ldb(WtT, (nt * 16 + p) * 128 + kb * 16 + q * 4), accT[nt]);
  }
  float r0f[4][4];
#pragma unroll
  for (int nt = 0; nt < 4; ++nt) {
    float bias = bt[nt * 16 + p];
#pragma unroll
    for (int r = 0; r < 4; ++r)
      r0f[nt][r] = sf[nt][r] * fmaxf(accT[nt][r] + bias, 0.f);
  }

  // ---- We0: m[j] = relu(s @ We0[j] + be0[j]), K=64, 32 cols each ----
  float mfr[4][2][4];
#pragma unroll
  for (int n = 0; n < 4; ++n) {
    f32x4 acc[2] = {z4, z4};
#pragma unroll
    for (int kb = 0; kb < 4; ++kb) {
      h16x4 a = ldx4(lrow + p, kb * 16 + q * 4);
#pragma unroll
      for (int nt = 0; nt < 2; ++nt)
        acc[nt] = MFMA16(a, ldb(We0T, (n * 32 + nt * 16 + p) * 64 + kb * 16 + q * 4), acc[nt]);
    }
#pragma unroll
    for (int nt = 0; nt < 2; ++nt) {
      float bias = be0[n * 32 + nt * 16 + p];
#pragma unroll
      for (int r = 0; r < 4; ++r) mfr[n][nt][r] = fmaxf(acc[nt][r] + bias, 0.f);
    }
  }

  // r0 -> x_lds
#pragma unroll
  for (int nt = 0; nt < 4; ++nt)
#pragma unroll
    for (int r = 0; r < 4; ++r) stx(lrow + 4 * q + r, nt * 16 + p, r0f[nt][r]);

  // ---- A0: softmax over groups of 4 of (r0 @ Wa0 + ba0) ----
  f32x4 accA = z4;
#pragma unroll
  for (int kb = 0; kb < 4; ++kb)
    accA = MFMA16(ldx4(lrow + p, kb * 16 + q * 4), ldb(Wa0T, p * 64 + kb * 16 + q * 4), accA);
  float a0v[4];
  {
    float bias = ba0[p];
#pragma unroll
    for (int r = 0; r < 4; ++r) {
      float v = accA[r] + bias;
      float mx = fmaxf(v, __shfl_xor(v, 1));
      mx = fmaxf(mx, __shfl_xor(mx, 2));
      float e = __expf(v - mx);
      float ssum = e + __shfl_xor(e, 1);
      ssum += __shfl_xor(ssum, 2);
      a0v[r] = e / ssum;
    }
  }
#pragma unroll
  for (int r = 0; r < 4; ++r)
    *(short*)(a_lds + (lrow + 4 * q + r) * 48 + p * 2) = h_bits(a0v[r]);

  // ---- combine: prev1[i][b][d] = sum_j a0[b][i][j] * m[j][b][d] ----
  float pv[4][2][4];
#pragma unroll
  for (int i = 0; i < 4; ++i)
#pragma unroll
    for (int nt = 0; nt < 2; ++nt)
#pragma unroll
      for (int r = 0; r < 4; ++r) pv[i][nt][r] = 0.f;
  const int sbase = lane & 48;
#pragma unroll
  for (int r = 0; r < 4; ++r) {
#pragma unroll
    for (int c = 0; c < 16; ++c) {
      float av = __shfl(a0v[r], sbase | c);
      pv[c >> 2][0][r] += av * mfr[c & 3][0][r];
      pv[c >> 2][1][r] += av * mfr[c & 3][1][r];
    }
  }

  // ---- Wc0: r = relu((a0 @ Wc0 + bc0) * r0), K=16 (one MFMA block) ----
  f32x4 accC[4] = {z4, z4, z4, z4};
  {
    h16x4 a = *(const h16x4*)(a_lds + (lrow + p) * 48 + q * 8);
#pragma unroll
    for (int nt = 0; nt < 4; ++nt)
      accC[nt] = MFMA16(a, ldb(Wc0T, (nt * 16 + p) * 16 + q * 4), accC[nt]);
  }
  float rf[4][4];
#pragma unroll
  for (int nt = 0; nt < 4; ++nt) {
    float bias = bc0[nt * 16 + p];
#pragma unroll
    for (int r = 0; r < 4; ++r)
      rf[nt][r] = fmaxf((accC[nt][r] + bias) * r0f[nt][r], 0.f);
  }
#pragma unroll
  for (int nt = 0; nt < 4; ++nt)
#pragma unroll
    for (int r = 0; r < 4; ++r) stx(lrow + 4 * q + r, nt * 16 + p, rf[nt][r]);

  // ---- A1: softmax(r @ Wa1 + ba1) ----
  f32x4 accA1 = z4;
#pragma unroll
  for (int kb = 0; kb < 4; ++kb)
    accA1 = MFMA16(ldx4(lrow + p, kb * 16 + q * 4), ldb(Wa1T, p * 64 + kb * 16 + q * 4), accA1);
  float a1v[4];
  {
    float bias = ba1[p];
#pragma unroll
    for (int r = 0; r < 4; ++r) {
      float v = accA1[r] + bias;
      float mx = fmaxf(v, __shfl_xor(v, 1));
      mx = fmaxf(mx, __shfl_xor(mx, 2));
      float e = __expf(v - mx);
      float ssum = e + __shfl_xor(e, 1);
      ssum += __shfl_xor(ssum, 2);
      a1v[r] = e / ssum;
    }
  }

  // ---- prev1 -> p_lds; E1: m1[n] = relu(prev1[n] @ We1[n] + be1[n]), K=32 ----
#pragma unroll
  for (int i = 0; i < 4; ++i)
#pragma unroll
    for (int nt = 0; nt < 2; ++nt)
#pragma unroll
      for (int r = 0; r < 4; ++r)
        *(short*)(p_lds + (i * 64 + lrow + 4 * q + r) * 80 + (nt * 16 + p) * 2) = h_bits(pv[i][nt][r]);

  float m1f[4][2][4];
#pragma unroll
  for (int n = 0; n < 4; ++n) {
    f32x4 acc[2] = {z4, z4};
#pragma unroll
    for (int kb = 0; kb < 2; ++kb) {
      h16x4 a = *(const h16x4*)(p_lds + (n * 64 + lrow + p) * 80 + kb * 32 + q * 8);
#pragma unroll
      for (int nt = 0; nt < 2; ++nt)
        acc[nt] = MFMA16(a, ldb(We1T, (n * 32 + nt * 16 + p) * 32 + kb * 16 + q * 4), acc[nt]);
    }
#pragma unroll
    for (int nt = 0; nt < 2; ++nt) {
      float bias = be1[n * 32 + nt * 16 + p];
#pragma unroll
      for (int r = 0; r < 4; ++r) m1f[n][nt][r] = fmaxf(acc[nt][r] + bias, 0.f);
    }
  }

  // ---- combine 2: prev2 = einsum(a1, m1) ----
#pragma unroll
  for (int i = 0; i < 4; ++i)
#pragma unroll
    for (int nt = 0; nt < 2; ++nt)
#pragma unroll
      for (int r = 0; r < 4; ++r) pv[i][nt][r] = 0.f;
#pragma unroll
  for (int r = 0; r < 4; ++r) {
#pragma unroll
    for (int c = 0; c < 16; ++c) {
      float av = __shfl(a1v[r], sbase | c);
      pv[c >> 2][0][r] += av * m1f[c & 3][0][r];
      pv[c >> 2][1][r] += av * m1f[c & 3][1][r];
    }
  }

  // ---- prev2 -> p_lds; E2 + relu + sum over n; store f32 ----
#pragma unroll
  for (int i = 0; i < 4; ++i)
#pragma unroll
    for (int nt = 0; nt < 2; ++nt)
#pragma unroll
      for (int r = 0; r < 4; ++r)
        *(short*)(p_lds + (i * 64 + lrow + 4 * q + r) * 80 + (nt * 16 + p) * 2) = h_bits(pv[i][nt][r]);

  float of[2][4] = {{0.f, 0.f, 0.f, 0.f}, {0.f, 0.f, 0.f, 0.f}};
#pragma unroll
  for (int n = 0; n < 4; ++n) {
    f32x4 acc[2] = {z4, z4};
#pragma unroll
    for (int kb = 0; kb < 2; ++kb) {
      h16x4 a = *(const h16x4*)(p_lds + (n * 64 + lrow + p) * 80 + kb * 32 + q * 8);
#pragma unroll
      for (int nt = 0; nt < 2; ++nt)
        acc[nt] = MFMA16(a, ldb(We2T, (n * 32 + nt * 16 + p) * 32 + kb * 16 + q * 4), acc[nt]);
    }
#pragma unroll
    for (int nt = 0; nt < 2; ++nt) {
      float bias = be2[n * 32 + nt * 16 + p];
#pragma unroll
      for (int r = 0; r < 4; ++r) of[nt][r] += fmaxf(acc[nt][r] + bias, 0.f);
    }
  }
#pragma unroll
  for (int nt = 0; nt < 2; ++nt)
#pragma unroll
    for (int r = 0; r < 4; ++r) {
      int grow = rowblk + 4 * q + r;
      out[(size_t)grow * 32 + nt * 16 + p] = of[nt][r];   // f32 output
    }
}

extern "C" void kernel_launch(void* const* d_in, const int* in_sizes, int n_in,
                              void* d_out, int out_size, void* d_ws, size_t ws_size,
                              hipStream_t stream) {
  (void)in_sizes; (void)n_in; (void)out_size; (void)ws_size;
  // Inputs in setup_inputs() dict order (all float32 per reference).
  const float* obs  = (const float*)d_in[0];
  const float* task = (const float*)d_in[1];
  const float* Ws1 = (const float*)d_in[2];  const float* bs1 = (const float*)d_in[3];
  const float* Ws2 = (const float*)d_in[4];  const float* bs2 = (const float*)d_in[5];
  const float* Wt  = (const float*)d_in[6];  const float* bt  = (const float*)d_in[7];
  const float* Wa0 = (const float*)d_in[8];  const float* ba0 = (const float*)d_in[9];
  const float* Wa1 = (const float*)d_in[10]; const float* ba1 = (const float*)d_in[11];
  const float* Wc0 = (const float*)d_in[12]; const float* bc0 = (const float*)d_in[13];
  // d_in[14]=Wc1, d_in[15]=bc1: dead code in the reference (result unused)
  const float* We0 = (const float*)d_in[16]; const float* be0 = (const float*)d_in[17];
  const float* We1 = (const float*)d_in[18]; const float* be1 = (const float*)d_in[19];
  const float* We2 = (const float*)d_in[20]; const float* be2 = (const float*)d_in[21];

  short* wsh   = (short*)d_ws;
  float* biasf = (float*)((char*)d_ws + 129040);  // 64512*2 rounded up to 16

  sm_convert_v3<<<dim3(255), dim3(256), 0, stream>>>(
      Ws1, Ws2, Wt, Wa0, Wa1, Wc0, We0, We1, We2,
      bs1, bs2, bt, ba0, ba1, bc0, be0, be1, be2,
      wsh, biasf);
  sm_fused_v3<<<dim3(1024), dim3(256), 0, stream>>>(
      obs, task, wsh, biasf, (float*)d_out);
}

// Round 4
// 82.620 us; speedup vs baseline: 1.6241x; 1.6241x over previous
//
#include <hip/hip_runtime.h>
#include <hip/hip_bf16.h>

// SoftModule fused forward, MI355X gfx950 — v4.
// v3 + DMA-pipelined streaming for obs/task via global_load_lds (per-wave
// double-buffered 1KB chunks, counted vmcnt) + packed B-fragments for Ws1/Wt.
// All other phases identical to v3 (verified PASS, absmax 0.031).

using f32x4 = __attribute__((ext_vector_type(4))) float;
using h16x4 = __attribute__((ext_vector_type(4))) _Float16;

#define MFMA16(a, b, c) __builtin_amdgcn_mfma_f32_16x16x16f16((a), (b), (c), 0, 0, 0)

__device__ __forceinline__ short h_bits(float f) {  // f32 -> f16 bits
  _Float16 h = (_Float16)f;
  return __builtin_bit_cast(short, h);
}

// async global->LDS, 16B per lane; lds base must be wave-uniform (HW adds lane*16)
__device__ __forceinline__ void dma16(const void* g, void* l) {
  __builtin_amdgcn_global_load_lds(
      (const __attribute__((address_space(1))) unsigned int*)g,
      (__attribute__((address_space(3))) unsigned int*)l, 16, 0, 0);
}

// ---------------- weight convert + transpose/pack to f16 --------------------
// wsh (f16) element offsets:
//   Bp1 [c32][q4][p16][nt4][kk4] @0      (packed Ws1; 32768)
//   Ws2T [64][64] @32768                 WtP [c8][q][p][nt][kk] @36864 (8192)
//   Wa0T [16][64] @45056   Wa1T [16][64] @46080   Wc0T [64][16] @47104
//   We0T [4][32][64] @48128  We1T [4][32][32] @56320  We2T [4][32][32] @60416
// biases f32 (672 floats) in biasf.
__global__ void sm_convert_v4(
    const float* __restrict__ Ws1, const float* __restrict__ Ws2, const float* __restrict__ Wt,
    const float* __restrict__ Wa0, const float* __restrict__ Wa1, const float* __restrict__ Wc0,
    const float* __restrict__ We0, const float* __restrict__ We1, const float* __restrict__ We2,
    const float* __restrict__ bs1, const float* __restrict__ bs2, const float* __restrict__ bt,
    const float* __restrict__ ba0, const float* __restrict__ ba1, const float* __restrict__ bc0,
    const float* __restrict__ be0, const float* __restrict__ be1, const float* __restrict__ be2,
    short* __restrict__ wsh, float* __restrict__ biasf) {
  int d = blockIdx.x * 256 + threadIdx.x;
  if (d < 64512) {
    float v;
    if (d < 32768) {             // Bp1: kk=d&3 nt=(d>>2)&3 p=(d>>4)&15 q=(d>>8)&3 c=d>>10
      int kk = d & 3, nt = (d >> 2) & 3, p = (d >> 4) & 15, q = (d >> 8) & 3, c = d >> 10;
      int k = c * 16 + q * 4 + kk, o = nt * 16 + p;
      v = Ws1[k * 64 + o];
    }
    else if (d < 36864) { int r = d - 32768, o = r >> 6, k = r & 63;   v = Ws2[k * 64 + o]; }
    else if (d < 45056) {        // WtP, 8192 elements
      int r = d - 36864;
      int kk = r & 3, nt = (r >> 2) & 3, p = (r >> 4) & 15, q = (r >> 8) & 3, c = r >> 10;
      int k = c * 16 + q * 4 + kk, o = nt * 16 + p;
      v = Wt[k * 64 + o];
    }
    else if (d < 46080) { int r = d - 45056, o = r >> 6, k = r & 63;   v = Wa0[k * 16 + o]; }
    else if (d < 47104) { int r = d - 46080, o = r >> 6, k = r & 63;   v = Wa1[k * 16 + o]; }
    else if (d < 48128) { int r = d - 47104, o = r >> 4, k = r & 15;   v = Wc0[k * 64 + o]; }
    else if (d < 56320) { int r = d - 48128, n = r >> 11, o = (r >> 6) & 31, i = r & 63; v = We0[n * 2048 + i * 32 + o]; }
    else if (d < 60416) { int r = d - 56320, n = r >> 10, o = (r >> 5) & 31, i = r & 31; v = We1[n * 1024 + i * 32 + o]; }
    else                { int r = d - 60416, n = r >> 10, o = (r >> 5) & 31, i = r & 31; v = We2[n * 1024 + i * 32 + o]; }
    wsh[d] = h_bits(v);
  } else if (d < 65184) {
    int r = d - 64512;
    float v;
    if      (r < 64)  v = bs1[r];
    else if (r < 128) v = bs2[r - 64];
    else if (r < 192) v = bt[r - 128];
    else if (r < 208) v = ba0[r - 192];
    else if (r < 224) v = ba1[r - 208];
    else if (r < 288) v = bc0[r - 224];
    else if (r < 416) v = be0[r - 288];
    else if (r < 544) v = be1[r - 416];
    else              v = be2[r - 544];
    biasf[r] = v;
  }
}

// ---------------- fused forward ---------------------------------------------
__global__ __launch_bounds__(256) void sm_fused_v4(
    const float* __restrict__ obs, const float* __restrict__ task,
    const short* __restrict__ wsh, const float* __restrict__ biasf,
    float* __restrict__ out) {
  const int tid  = threadIdx.x;
  const int wave = tid >> 6;
  const int lane = tid & 63;
  const int q    = lane >> 4;   // k-group (A/B) / row-reg group (C/D)
  const int p    = lane & 15;   // row (A) / col (B, C/D)
  const int lrow = wave * 16;
  const int rowblk = blockIdx.x * 64 + lrow;

  // LDS: 9216(x) + 3072(a) + 8192(ring) + 20480(p) = 40960 -> 4 blocks/CU
  __shared__ __align__(16) char lds[9216 + 3072 + 8192 + 20480];
  char* x_lds = lds;                        // [64 rows] stride 144B : 64 f16 cols
  char* a_lds = lds + 9216;                 // [64 rows] stride 48B  : 16 f16 cols
  char* ring  = lds + 12288 + wave * 2048;  // per-wave 2 x 1024B chunk buffers
  char* p_lds = lds + 20480;                // [4][64 rows] stride 80B: 32 f16 cols

  const short* Bp1  = wsh;            // packed Ws1
  const short* Ws2T = wsh + 32768;
  const short* WtP  = wsh + 36864;    // packed Wt
  const short* Wa0T = wsh + 45056;
  const short* Wa1T = wsh + 46080;
  const short* Wc0T = wsh + 47104;
  const short* We0T = wsh + 48128;
  const short* We1T = wsh + 56320;
  const short* We2T = wsh + 60416;
  const float* bs1 = biasf;        const float* bs2 = biasf + 64;
  const float* bt  = biasf + 128;  const float* ba0 = biasf + 192;
  const float* ba1 = biasf + 208;  const float* bc0 = biasf + 224;
  const float* be0 = biasf + 288;  const float* be1 = biasf + 416;
  const float* be2 = biasf + 544;

  const f32x4 z4 = {0.f, 0.f, 0.f, 0.f};

  auto stx  = [&](int row, int col, float v) { *(short*)(x_lds + row * 144 + col * 2) = h_bits(v); };
  auto ldx4 = [&](int row, int k0) -> h16x4 { return *(const h16x4*)(x_lds + row * 144 + k0 * 2); };
  auto ldb  = [&](const short* W, int off) -> h16x4 { return *(const h16x4*)(W + off); };
  // chunk: 16 rows x 16 f32 (1024B). lane l -> row l>>2, col (l&3)*4, LDS linear l*16.
  auto cvt4 = [&](const float4& v) -> h16x4 {
    h16x4 a;
    a[0] = (_Float16)v.x; a[1] = (_Float16)v.y;
    a[2] = (_Float16)v.z; a[3] = (_Float16)v.w;
    return a;
  };

  // ---- S1: X1 = relu(obs @ Ws1 + bs1), K=512, DMA-pipelined (32 chunks) ----
  f32x4 accX[4] = {z4, z4, z4, z4};
  {
    const float* srow = obs + (size_t)(rowblk + (lane >> 2)) * 512 + (lane & 3) * 4;
    dma16(srow, ring);                       // stage chunk 0 -> slot 0
    for (int c = 0; c < 32; ++c) {
      if (c + 1 < 32) {
        dma16(srow + (c + 1) * 16, ring + ((c + 1) & 1) * 1024);
        asm volatile("s_waitcnt vmcnt(1)" ::: "memory");   // chunk c landed
      } else {
        asm volatile("s_waitcnt vmcnt(0)" ::: "memory");
      }
      const char* sb = ring + (c & 1) * 1024;
      h16x4 a = cvt4(*(const float4*)(sb + p * 64 + q * 16));
      const short* bp = Bp1 + ((c * 4 + q) * 16 + p) * 16;  // 4 frags, 32B contig
#pragma unroll
      for (int nt = 0; nt < 4; ++nt)
        accX[nt] = MFMA16(a, ldb(bp, nt * 4), accX[nt]);
    }
  }
#pragma unroll
  for (int nt = 0; nt < 4; ++nt) {
    float bias = bs1[nt * 16 + p];
#pragma unroll
    for (int r = 0; r < 4; ++r)
      stx(lrow + 4 * q + r, nt * 16 + p, fmaxf(accX[nt][r] + bias, 0.f));
  }

  // ---- S2: s = relu(X1 @ Ws2 + bs2), K=64 ----
  f32x4 accS[4] = {z4, z4, z4, z4};
#pragma unroll
  for (int kb = 0; kb < 4; ++kb) {
    h16x4 a = ldx4(lrow + p, kb * 16 + q * 4);
#pragma unroll
    for (int nt = 0; nt < 4; ++nt)
      accS[nt] = MFMA16(a, ldb(Ws2T, (nt * 16 + p) * 64 + kb * 16 + q * 4), accS[nt]);
  }
  float sf[4][4];
#pragma unroll
  for (int nt = 0; nt < 4; ++nt) {
    float bias = bs2[nt * 16 + p];
#pragma unroll
    for (int r = 0; r < 4; ++r) sf[nt][r] = fmaxf(accS[nt][r] + bias, 0.f);
  }
#pragma unroll
  for (int nt = 0; nt < 4; ++nt)
#pragma unroll
    for (int r = 0; r < 4; ++r) stx(lrow + 4 * q + r, nt * 16 + p, sf[nt][r]);

  // ---- T: t = relu(task @ Wt + bt), K=128, DMA-pipelined (8 chunks) ----
  f32x4 accT[4] = {z4, z4, z4, z4};
  {
    const float* srow = task + (size_t)(rowblk + (lane >> 2)) * 128 + (lane & 3) * 4;
    dma16(srow, ring);
    for (int c = 0; c < 8; ++c) {
      if (c + 1 < 8) {
        dma16(srow + (c + 1) * 16, ring + ((c + 1) & 1) * 1024);
        asm volatile("s_waitcnt vmcnt(1)" ::: "memory");
      } else {
        asm volatile("s_waitcnt vmcnt(0)" ::: "memory");
      }
      const char* sb = ring + (c & 1) * 1024;
      h16x4 a = cvt4(*(const float4*)(sb + p * 64 + q * 16));
      const short* bp = WtP + ((c * 4 + q) * 16 + p) * 16;
#pragma unroll
      for (int nt = 0; nt < 4; ++nt)
        accT[nt] = MFMA16(a, ldb(bp, nt * 4), accT[nt]);
    }
  }
  float r0f[4][4];
#pragma unroll
  for (int nt = 0; nt < 4; ++nt) {
    float bias = bt[nt * 16 + p];
#pragma unroll
    for (int r = 0; r < 4; ++r)
      r0f[nt][r] = sf[nt][r] * fmaxf(accT[nt][r] + bias, 0.f);
  }

  // ---- We0: m[j] = relu(s @ We0[j] + be0[j]), K=64, 32 cols each ----
  float mfr[4][2][4];
#pragma unroll
  for (int n = 0; n < 4; ++n) {
    f32x4 acc[2] = {z4, z4};
#pragma unroll
    for (int kb = 0; kb < 4; ++kb) {
      h16x4 a = ldx4(lrow + p, kb * 16 + q * 4);
#pragma unroll
      for (int nt = 0; nt < 2; ++nt)
        acc[nt] = MFMA16(a, ldb(We0T, (n * 32 + nt * 16 + p) * 64 + kb * 16 + q * 4), acc[nt]);
    }
#pragma unroll
    for (int nt = 0; nt < 2; ++nt) {
      float bias = be0[n * 32 + nt * 16 + p];
#pragma unroll
      for (int r = 0; r < 4; ++r) mfr[n][nt][r] = fmaxf(acc[nt][r] + bias, 0.f);
    }
  }

  // r0 -> x_lds
#pragma unroll
  for (int nt = 0; nt < 4; ++nt)
#pragma unroll
    for (int r = 0; r < 4; ++r) stx(lrow + 4 * q + r, nt * 16 + p, r0f[nt][r]);

  // ---- A0: softmax over groups of 4 of (r0 @ Wa0 + ba0) ----
  f32x4 accA = z4;
#pragma unroll
  for (int kb = 0; kb < 4; ++kb)
    accA = MFMA16(ldx4(lrow + p, kb * 16 + q * 4), ldb(Wa0T, p * 64 + kb * 16 + q * 4), accA);
  float a0v[4];
  {
    float bias = ba0[p];
#pragma unroll
    for (int r = 0; r < 4; ++r) {
      float v = accA[r] + bias;
      float mx = fmaxf(v, __shfl_xor(v, 1));
      mx = fmaxf(mx, __shfl_xor(mx, 2));
      float e = __expf(v - mx);
      float ssum = e + __shfl_xor(e, 1);
      ssum += __shfl_xor(ssum, 2);
      a0v[r] = e / ssum;
    }
  }
#pragma unroll
  for (int r = 0; r < 4; ++r)
    *(short*)(a_lds + (lrow + 4 * q + r) * 48 + p * 2) = h_bits(a0v[r]);

  // ---- combine: prev1[i][b][d] = sum_j a0[b][i][j] * m[j][b][d] ----
  float pv[4][2][4];
#pragma unroll
  for (int i = 0; i < 4; ++i)
#pragma unroll
    for (int nt = 0; nt < 2; ++nt)
#pragma unroll
      for (int r = 0; r < 4; ++r) pv[i][nt][r] = 0.f;
  const int sbase = lane & 48;
#pragma unroll
  for (int r = 0; r < 4; ++r) {
#pragma unroll
    for (int c = 0; c < 16; ++c) {
      float av = __shfl(a0v[r], sbase | c);
      pv[c >> 2][0][r] += av * mfr[c & 3][0][r];
      pv[c >> 2][1][r] += av * mfr[c & 3][1][r];
    }
  }

  // ---- Wc0: r = relu((a0 @ Wc0 + bc0) * r0), K=16 (one MFMA block) ----
  f32x4 accC[4] = {z4, z4, z4, z4};
  {
    h16x4 a = *(const h16x4*)(a_lds + (lrow + p) * 48 + q * 8);
#pragma unroll
    for (int nt = 0; nt < 4; ++nt)
      accC[nt] = MFMA16(a, ldb(Wc0T, (nt * 16 + p) * 16 + q * 4), accC[nt]);
  }
  float rf[4][4];
#pragma unroll
  for (int nt = 0; nt < 4; ++nt) {
    float bias = bc0[nt * 16 + p];
#pragma unroll
    for (int r = 0; r < 4; ++r)
      rf[nt][r] = fmaxf((accC[nt][r] + bias) * r0f[nt][r], 0.f);
  }
#pragma unroll
  for (int nt = 0; nt < 4; ++nt)
#pragma unroll
    for (int r = 0; r < 4; ++r) stx(lrow + 4 * q + r, nt * 16 + p, rf[nt][r]);

  // ---- A1: softmax(r @ Wa1 + ba1) ----
  f32x4 accA1 = z4;
#pragma unroll
  for (int kb = 0; kb < 4; ++kb)
    accA1 = MFMA16(ldx4(lrow + p, kb * 16 + q * 4), ldb(Wa1T, p * 64 + kb * 16 + q * 4), accA1);
  float a1v[4];
  {
    float bias = ba1[p];
#pragma unroll
    for (int r = 0; r < 4; ++r) {
      float v = accA1[r] + bias;
      float mx = fmaxf(v, __shfl_xor(v, 1));
      mx = fmaxf(mx, __shfl_xor(mx, 2));
      float e = __expf(v - mx);
      float ssum = e + __shfl_xor(e, 1);
      ssum += __shfl_xor(ssum, 2);
      a1v[r] = e / ssum;
    }
  }

  // ---- prev1 -> p_lds; E1: m1[n] = relu(prev1[n] @ We1[n] + be1[n]), K=32 ----
#pragma unroll
  for (int i = 0; i < 4; ++i)
#pragma unroll
    for (int nt = 0; nt < 2; ++nt)
#pragma unroll
      for (int r = 0; r < 4; ++r)
        *(short*)(p_lds + (i * 64 + lrow + 4 * q + r) * 80 + (nt * 16 + p) * 2) = h_bits(pv[i][nt][r]);

  float m1f[4][2][4];
#pragma unroll
  for (int n = 0; n < 4; ++n) {
    f32x4 acc[2] = {z4, z4};
#pragma unroll
    for (int kb = 0; kb < 2; ++kb) {
      h16x4 a = *(const h16x4*)(p_lds + (n * 64 + lrow + p) * 80 + kb * 32 + q * 8);
#pragma unroll
      for (int nt = 0; nt < 2; ++nt)
        acc[nt] = MFMA16(a, ldb(We1T, (n * 32 + nt * 16 + p) * 32 + kb * 16 + q * 4), acc[nt]);
    }
#pragma unroll
    for (int nt = 0; nt < 2; ++nt) {
      float bias = be1[n * 32 + nt * 16 + p];
#pragma unroll
      for (int r = 0; r < 4; ++r) m1f[n][nt][r] = fmaxf(acc[nt][r] + bias, 0.f);
    }
  }

  // ---- combine 2: prev2 = einsum(a1, m1) ----
#pragma unroll
  for (int i = 0; i < 4; ++i)
#pragma unroll
    for (int nt = 0; nt < 2; ++nt)
#pragma unroll
      for (int r = 0; r < 4; ++r) pv[i][nt][r] = 0.f;
#pragma unroll
  for (int r = 0; r < 4; ++r) {
#pragma unroll
    for (int c = 0; c < 16; ++c) {
      float av = __shfl(a1v[r], sbase | c);
      pv[c >> 2][0][r] += av * m1f[c & 3][0][r];
      pv[c >> 2][1][r] += av * m1f[c & 3][1][r];
    }
  }

  // ---- prev2 -> p_lds; E2 + relu + sum over n; store f32 ----
#pragma unroll
  for (int i = 0; i < 4; ++i)
#pragma unroll
    for (int nt = 0; nt < 2; ++nt)
#pragma unroll
      for (int r = 0; r < 4; ++r)
        *(short*)(p_lds + (i * 64 + lrow + 4 * q + r) * 80 + (nt * 16 + p) * 2) = h_bits(pv[i][nt][r]);

  float of[2][4] = {{0.f, 0.f, 0.f, 0.f}, {0.f, 0.f, 0.f, 0.f}};
#pragma unroll
  for (int n = 0; n < 4; ++n) {
    f32x4 acc[2] = {z4, z4};
#pragma unroll
    for (int kb = 0; kb < 2; ++kb) {
      h16x4 a = *(const h16x4*)(p_lds + (n * 64 + lrow + p) * 80 + kb * 32 + q * 8);
#pragma unroll
      for (int nt = 0; nt < 2; ++nt)
        acc[nt] = MFMA16(a, ldb(We2T, (n * 32 + nt * 16 + p) * 32 + kb * 16 + q * 4), acc[nt]);
    }
#pragma unroll
    for (int nt = 0; nt < 2; ++nt) {
      float bias = be2[n * 32 + nt * 16 + p];
#pragma unroll
      for (int r = 0; r < 4; ++r) of[nt][r] += fmaxf(acc[nt][r] + bias, 0.f);
    }
  }
#pragma unroll
  for (int nt = 0; nt < 2; ++nt)
#pragma unroll
    for (int r = 0; r < 4; ++r) {
      int grow = rowblk + 4 * q + r;
      out[(size_t)grow * 32 + nt * 16 + p] = of[nt][r];
    }
}

extern "C" void kernel_launch(void* const* d_in, const int* in_sizes, int n_in,
                              void* d_out, int out_size, void* d_ws, size_t ws_size,
                              hipStream_t stream) {
  (void)in_sizes; (void)n_in; (void)out_size; (void)ws_size;
  const float* obs  = (const float*)d_in[0];
  const float* task = (const float*)d_in[1];
  const float* Ws1 = (const float*)d_in[2];  const float* bs1 = (const float*)d_in[3];
  const float* Ws2 = (const float*)d_in[4];  const float* bs2 = (const float*)d_in[5];
  const float* Wt  = (const float*)d_in[6];  const float* bt  = (const float*)d_in[7];
  const float* Wa0 = (const float*)d_in[8];  const float* ba0 = (const float*)d_in[9];
  const float* Wa1 = (const float*)d_in[10]; const float* ba1 = (const float*)d_in[11];
  const float* Wc0 = (const float*)d_in[12]; const float* bc0 = (const float*)d_in[13];
  // d_in[14]=Wc1, d_in[15]=bc1: dead code in the reference (result unused)
  const float* We0 = (const float*)d_in[16]; const float* be0 = (const float*)d_in[17];
  const float* We1 = (const float*)d_in[18]; const float* be1 = (const float*)d_in[19];
  const float* We2 = (const float*)d_in[20]; const float* be2 = (const float*)d_in[21];

  short* wsh   = (short*)d_ws;
  float* biasf = (float*)((char*)d_ws + 129040);

  sm_convert_v4<<<dim3(255), dim3(256), 0, stream>>>(
      Ws1, Ws2, Wt, Wa0, Wa1, Wc0, We0, We1, We2,
      bs1, bs2, bt, ba0, ba1, bc0, be0, be1, be2,
      wsh, biasf);
  sm_fused_v4<<<dim3(1024), dim3(256), 0, stream>>>(
      obs, task, wsh, biasf, (float*)d_out);
}

// Round 5
// 80.532 us; speedup vs baseline: 1.6662x; 1.0259x over previous
//
#include <hip/hip_runtime.h>
#include <hip/hip_bf16.h>

// SoftModule fused forward, MI355X gfx950 — v5.
// v4 + fixed vmem-FIFO accounting in S1/T loops (B-frag loads inside the
// counted vmcnt window; sched_barrier pins DMA as youngest op) + LDS overlay
// (p_lds over x/a/ring after one __syncthreads) shrinking LDS 40960->20480.

using f32x4 = __attribute__((ext_vector_type(4))) float;
using h16x4 = __attribute__((ext_vector_type(4))) _Float16;
using u32x4 = __attribute__((ext_vector_type(4))) unsigned int;
using u32x2 = __attribute__((ext_vector_type(2))) unsigned int;

#define MFMA16(a, b, c) __builtin_amdgcn_mfma_f32_16x16x16f16((a), (b), (c), 0, 0, 0)

__device__ __forceinline__ short h_bits(float f) {  // f32 -> f16 bits
  _Float16 h = (_Float16)f;
  return __builtin_bit_cast(short, h);
}

// async global->LDS, 16B per lane; lds base wave-uniform (HW adds lane*16)
__device__ __forceinline__ void dma16(const void* g, void* l) {
  __builtin_amdgcn_global_load_lds(
      (const __attribute__((address_space(1))) unsigned int*)g,
      (__attribute__((address_space(3))) unsigned int*)l, 16, 0, 0);
}

// ---------------- weight convert + transpose/pack to f16 --------------------
// wsh (f16) element offsets:
//   Bp1 [c32][q4][p16][nt4][kk4] @0      (packed Ws1; 32768)
//   Ws2T [64][64] @32768                 WtP [c8][q][p][nt][kk] @36864 (8192)
//   Wa0T [16][64] @45056   Wa1T [16][64] @46080   Wc0T [64][16] @47104
//   We0T [4][32][64] @48128  We1T [4][32][32] @56320  We2T [4][32][32] @60416
// biases f32 (672 floats) in biasf.
__global__ void sm_convert_v5(
    const float* __restrict__ Ws1, const float* __restrict__ Ws2, const float* __restrict__ Wt,
    const float* __restrict__ Wa0, const float* __restrict__ Wa1, const float* __restrict__ Wc0,
    const float* __restrict__ We0, const float* __restrict__ We1, const float* __restrict__ We2,
    const float* __restrict__ bs1, const float* __restrict__ bs2, const float* __restrict__ bt,
    const float* __restrict__ ba0, const float* __restrict__ ba1, const float* __restrict__ bc0,
    const float* __restrict__ be0, const float* __restrict__ be1, const float* __restrict__ be2,
    short* __restrict__ wsh, float* __restrict__ biasf) {
  int d = blockIdx.x * 256 + threadIdx.x;
  if (d < 64512) {
    float v;
    if (d < 32768) {             // Bp1
      int kk = d & 3, nt = (d >> 2) & 3, p = (d >> 4) & 15, q = (d >> 8) & 3, c = d >> 10;
      int k = c * 16 + q * 4 + kk, o = nt * 16 + p;
      v = Ws1[k * 64 + o];
    }
    else if (d < 36864) { int r = d - 32768, o = r >> 6, k = r & 63;   v = Ws2[k * 64 + o]; }
    else if (d < 45056) {        // WtP
      int r = d - 36864;
      int kk = r & 3, nt = (r >> 2) & 3, p = (r >> 4) & 15, q = (r >> 8) & 3, c = r >> 10;
      int k = c * 16 + q * 4 + kk, o = nt * 16 + p;
      v = Wt[k * 64 + o];
    }
    else if (d < 46080) { int r = d - 45056, o = r >> 6, k = r & 63;   v = Wa0[k * 16 + o]; }
    else if (d < 47104) { int r = d - 46080, o = r >> 6, k = r & 63;   v = Wa1[k * 16 + o]; }
    else if (d < 48128) { int r = d - 47104, o = r >> 4, k = r & 15;   v = Wc0[k * 64 + o]; }
    else if (d < 56320) { int r = d - 48128, n = r >> 11, o = (r >> 6) & 31, i = r & 63; v = We0[n * 2048 + i * 32 + o]; }
    else if (d < 60416) { int r = d - 56320, n = r >> 10, o = (r >> 5) & 31, i = r & 31; v = We1[n * 1024 + i * 32 + o]; }
    else                { int r = d - 60416, n = r >> 10, o = (r >> 5) & 31, i = r & 31; v = We2[n * 1024 + i * 32 + o]; }
    wsh[d] = h_bits(v);
  } else if (d < 65184) {
    int r = d - 64512;
    float v;
    if      (r < 64)  v = bs1[r];
    else if (r < 128) v = bs2[r - 64];
    else if (r < 192) v = bt[r - 128];
    else if (r < 208) v = ba0[r - 192];
    else if (r < 224) v = ba1[r - 208];
    else if (r < 288) v = bc0[r - 224];
    else if (r < 416) v = be0[r - 288];
    else if (r < 544) v = be1[r - 416];
    else              v = be2[r - 544];
    biasf[r] = v;
  }
}

// ---------------- fused forward ---------------------------------------------
__global__ __launch_bounds__(256) void sm_fused_v5(
    const float* __restrict__ obs, const float* __restrict__ task,
    const short* __restrict__ wsh, const float* __restrict__ biasf,
    float* __restrict__ out) {
  const int tid  = threadIdx.x;
  const int wave = tid >> 6;
  const int lane = tid & 63;
  const int q    = lane >> 4;   // k-group (A/B) / row-reg group (C/D)
  const int p    = lane & 15;   // row (A) / col (B, C/D)
  const int lrow = wave * 16;
  const int rowblk = blockIdx.x * 64 + lrow;

  // LDS 20480B total (8 WG/CU capacity).
  // Pre-barrier:  x[64 rows, stride 144] @0 | a[64 rows, stride 48] @9216 |
  //               ring[4 waves][2x1KB] @12288
  // Post-barrier: p[4][64 rows, stride 80] overlays everything @0
  __shared__ __align__(16) char lds[20480];
  char* x_lds = lds;
  char* a_lds = lds + 9216;
  char* ring  = lds + 12288 + wave * 2048;
  char* p_lds = lds;   // valid only after the barrier

  const short* Bp1  = wsh;            // packed Ws1
  const short* Ws2T = wsh + 32768;
  const short* WtP  = wsh + 36864;    // packed Wt
  const short* Wa0T = wsh + 45056;
  const short* Wa1T = wsh + 46080;
  const short* Wc0T = wsh + 47104;
  const short* We0T = wsh + 48128;
  const short* We1T = wsh + 56320;
  const short* We2T = wsh + 60416;
  const float* bs1 = biasf;        const float* bs2 = biasf + 64;
  const float* bt  = biasf + 128;  const float* ba0 = biasf + 192;
  const float* ba1 = biasf + 208;  const float* bc0 = biasf + 224;
  const float* be0 = biasf + 288;  const float* be1 = biasf + 416;
  const float* be2 = biasf + 544;

  const f32x4 z4 = {0.f, 0.f, 0.f, 0.f};

  auto stx  = [&](int row, int col, float v) { *(short*)(x_lds + row * 144 + col * 2) = h_bits(v); };
  auto ldx4 = [&](int row, int k0) -> h16x4 { return *(const h16x4*)(x_lds + row * 144 + k0 * 2); };
  auto ldb  = [&](const short* W, int off) -> h16x4 { return *(const h16x4*)(W + off); };
  auto cvt4 = [&](const float4& v) -> h16x4 {
    h16x4 a;
    a[0] = (_Float16)v.x; a[1] = (_Float16)v.y;
    a[2] = (_Float16)v.z; a[3] = (_Float16)v.w;
    return a;
  };

  // ---- S1: X1 = relu(obs @ Ws1 + bs1), K=512, DMA-pipelined (32 chunks) ----
  // Per iter exactly 3 vmem ops BEFORE the wait: B(c) as 2x dwordx4, then the
  // dma (pinned youngest by sched_barrier). FIFO at wait:
  // [dma(c), Ba, Bb, dma(c+1)] -> vmcnt(1) retires chunk c + B(c), keeps c+1.
  f32x4 accX[4] = {z4, z4, z4, z4};
  {
    const float* srow = obs + (size_t)(rowblk + (lane >> 2)) * 512 + (lane & 3) * 4;
    dma16(srow, ring);                       // chunk 0 -> slot 0
    for (int c = 0; c < 32; ++c) {
      const short* bp = Bp1 + ((c * 4 + q) * 16 + p) * 16;  // 32B contiguous
      u32x4 b01 = *(const u32x4*)bp;
      u32x4 b23 = *(const u32x4*)(bp + 8);
      __builtin_amdgcn_sched_barrier(0);     // keep B loads older than the dma
      if (c + 1 < 32) {
        dma16(srow + (c + 1) * 16, ring + ((c + 1) & 1) * 1024);
        asm volatile("s_waitcnt vmcnt(1)" ::: "memory");
      } else {
        asm volatile("s_waitcnt vmcnt(0)" ::: "memory");
      }
      const char* sb = ring + (c & 1) * 1024;
      h16x4 a = cvt4(*(const float4*)(sb + p * 64 + q * 16));
      h16x4 bf0 = __builtin_bit_cast(h16x4, (u32x2){b01[0], b01[1]});
      h16x4 bf1 = __builtin_bit_cast(h16x4, (u32x2){b01[2], b01[3]});
      h16x4 bf2 = __builtin_bit_cast(h16x4, (u32x2){b23[0], b23[1]});
      h16x4 bf3 = __builtin_bit_cast(h16x4, (u32x2){b23[2], b23[3]});
      accX[0] = MFMA16(a, bf0, accX[0]);
      accX[1] = MFMA16(a, bf1, accX[1]);
      accX[2] = MFMA16(a, bf2, accX[2]);
      accX[3] = MFMA16(a, bf3, accX[3]);
    }
  }
#pragma unroll
  for (int nt = 0; nt < 4; ++nt) {
    float bias = bs1[nt * 16 + p];
#pragma unroll
    for (int r = 0; r < 4; ++r)
      stx(lrow + 4 * q + r, nt * 16 + p, fmaxf(accX[nt][r] + bias, 0.f));
  }

  // ---- S2: s = relu(X1 @ Ws2 + bs2), K=64 ----
  f32x4 accS[4] = {z4, z4, z4, z4};
#pragma unroll
  for (int kb = 0; kb < 4; ++kb) {
    h16x4 a = ldx4(lrow + p, kb * 16 + q * 4);
#pragma unroll
    for (int nt = 0; nt < 4; ++nt)
      accS[nt] = MFMA16(a, ldb(Ws2T, (nt * 16 + p) * 64 + kb * 16 + q * 4), accS[nt]);
  }
  float sf[4][4];
#pragma unroll
  for (int nt = 0; nt < 4; ++nt) {
    float bias = bs2[nt * 16 + p];
#pragma unroll
    for (int r = 0; r < 4; ++r) sf[nt][r] = fmaxf(accS[nt][r] + bias, 0.f);
  }
#pragma unroll
  for (int nt = 0; nt < 4; ++nt)
#pragma unroll
    for (int r = 0; r < 4; ++r) stx(lrow + 4 * q + r, nt * 16 + p, sf[nt][r]);

  // ---- T: t = relu(task @ Wt + bt), K=128, DMA-pipelined (8 chunks) ----
  f32x4 accT[4] = {z4, z4, z4, z4};
  {
    const float* srow = task + (size_t)(rowblk + (lane >> 2)) * 128 + (lane & 3) * 4;
    dma16(srow, ring);
    for (int c = 0; c < 8; ++c) {
      const short* bp = WtP + ((c * 4 + q) * 16 + p) * 16;
      u32x4 b01 = *(const u32x4*)bp;
      u32x4 b23 = *(const u32x4*)(bp + 8);
      __builtin_amdgcn_sched_barrier(0);
      if (c + 1 < 8) {
        dma16(srow + (c + 1) * 16, ring + ((c + 1) & 1) * 1024);
        asm volatile("s_waitcnt vmcnt(1)" ::: "memory");
      } else {
        asm volatile("s_waitcnt vmcnt(0)" ::: "memory");
      }
      const char* sb = ring + (c & 1) * 1024;
      h16x4 a = cvt4(*(const float4*)(sb + p * 64 + q * 16));
      h16x4 bf0 = __builtin_bit_cast(h16x4, (u32x2){b01[0], b01[1]});
      h16x4 bf1 = __builtin_bit_cast(h16x4, (u32x2){b01[2], b01[3]});
      h16x4 bf2 = __builtin_bit_cast(h16x4, (u32x2){b23[0], b23[1]});
      h16x4 bf3 = __builtin_bit_cast(h16x4, (u32x2){b23[2], b23[3]});
      accT[0] = MFMA16(a, bf0, accT[0]);
      accT[1] = MFMA16(a, bf1, accT[1]);
      accT[2] = MFMA16(a, bf2, accT[2]);
      accT[3] = MFMA16(a, bf3, accT[3]);
    }
  }
  float r0f[4][4];
#pragma unroll
  for (int nt = 0; nt < 4; ++nt) {
    float bias = bt[nt * 16 + p];
#pragma unroll
    for (int r = 0; r < 4; ++r)
      r0f[nt][r] = sf[nt][r] * fmaxf(accT[nt][r] + bias, 0.f);
  }

  // ---- We0: m[j] = relu(s @ We0[j] + be0[j]), K=64, 32 cols each ----
  float mfr[4][2][4];
#pragma unroll
  for (int n = 0; n < 4; ++n) {
    f32x4 acc[2] = {z4, z4};
#pragma unroll
    for (int kb = 0; kb < 4; ++kb) {
      h16x4 a = ldx4(lrow + p, kb * 16 + q * 4);
#pragma unroll
      for (int nt = 0; nt < 2; ++nt)
        acc[nt] = MFMA16(a, ldb(We0T, (n * 32 + nt * 16 + p) * 64 + kb * 16 + q * 4), acc[nt]);
    }
#pragma unroll
    for (int nt = 0; nt < 2; ++nt) {
      float bias = be0[n * 32 + nt * 16 + p];
#pragma unroll
      for (int r = 0; r < 4; ++r) mfr[n][nt][r] = fmaxf(acc[nt][r] + bias, 0.f);
    }
  }

  // r0 -> x_lds
#pragma unroll
  for (int nt = 0; nt < 4; ++nt)
#pragma unroll
    for (int r = 0; r < 4; ++r) stx(lrow + 4 * q + r, nt * 16 + p, r0f[nt][r]);

  // ---- A0: softmax over groups of 4 of (r0 @ Wa0 + ba0) ----
  f32x4 accA = z4;
#pragma unroll
  for (int kb = 0; kb < 4; ++kb)
    accA = MFMA16(ldx4(lrow + p, kb * 16 + q * 4), ldb(Wa0T, p * 64 + kb * 16 + q * 4), accA);
  float a0v[4];
  {
    float bias = ba0[p];
#pragma unroll
    for (int r = 0; r < 4; ++r) {
      float v = accA[r] + bias;
      float mx = fmaxf(v, __shfl_xor(v, 1));
      mx = fmaxf(mx, __shfl_xor(mx, 2));
      float e = __expf(v - mx);
      float ssum = e + __shfl_xor(e, 1);
      ssum += __shfl_xor(ssum, 2);
      a0v[r] = e / ssum;
    }
  }
#pragma unroll
  for (int r = 0; r < 4; ++r)
    *(short*)(a_lds + (lrow + 4 * q + r) * 48 + p * 2) = h_bits(a0v[r]);

  // ---- combine: prev1[i][b][d] = sum_j a0[b][i][j] * m[j][b][d] ----
  float pv[4][2][4];
#pragma unroll
  for (int i = 0; i < 4; ++i)
#pragma unroll
    for (int nt = 0; nt < 2; ++nt)
#pragma unroll
      for (int r = 0; r < 4; ++r) pv[i][nt][r] = 0.f;
  const int sbase = lane & 48;
#pragma unroll
  for (int r = 0; r < 4; ++r) {
#pragma unroll
    for (int c = 0; c < 16; ++c) {
      float av = __shfl(a0v[r], sbase | c);
      pv[c >> 2][0][r] += av * mfr[c & 3][0][r];
      pv[c >> 2][1][r] += av * mfr[c & 3][1][r];
    }
  }

  // ---- Wc0: r = relu((a0 @ Wc0 + bc0) * r0), K=16 (one MFMA block) ----
  f32x4 accC[4] = {z4, z4, z4, z4};
  {
    h16x4 a = *(const h16x4*)(a_lds + (lrow + p) * 48 + q * 8);
#pragma unroll
    for (int nt = 0; nt < 4; ++nt)
      accC[nt] = MFMA16(a, ldb(Wc0T, (nt * 16 + p) * 16 + q * 4), accC[nt]);
  }
  float rf[4][4];
#pragma unroll
  for (int nt = 0; nt < 4; ++nt) {
    float bias = bc0[nt * 16 + p];
#pragma unroll
    for (int r = 0; r < 4; ++r)
      rf[nt][r] = fmaxf((accC[nt][r] + bias) * r0f[nt][r], 0.f);
  }
#pragma unroll
  for (int nt = 0; nt < 4; ++nt)
#pragma unroll
    for (int r = 0; r < 4; ++r) stx(lrow + 4 * q + r, nt * 16 + p, rf[nt][r]);

  // ---- A1: softmax(r @ Wa1 + ba1) ----
  f32x4 accA1 = z4;
#pragma unroll
  for (int kb = 0; kb < 4; ++kb)
    accA1 = MFMA16(ldx4(lrow + p, kb * 16 + q * 4), ldb(Wa1T, p * 64 + kb * 16 + q * 4), accA1);
  float a1v[4];
  {
    float bias = ba1[p];
#pragma unroll
    for (int r = 0; r < 4; ++r) {
      float v = accA1[r] + bias;
      float mx = fmaxf(v, __shfl_xor(v, 1));
      mx = fmaxf(mx, __shfl_xor(mx, 2));
      float e = __expf(v - mx);
      float ssum = e + __shfl_xor(e, 1);
      ssum += __shfl_xor(ssum, 2);
      a1v[r] = e / ssum;
    }
  }

  // ---- barrier: x/a/ring are dead for ALL waves; p_lds overlays them ----
  __syncthreads();

  // ---- prev1 -> p_lds; E1: m1[n] = relu(prev1[n] @ We1[n] + be1[n]), K=32 ----
#pragma unroll
  for (int i = 0; i < 4; ++i)
#pragma unroll
    for (int nt = 0; nt < 2; ++nt)
#pragma unroll
      for (int r = 0; r < 4; ++r)
        *(short*)(p_lds + (i * 64 + lrow + 4 * q + r) * 80 + (nt * 16 + p) * 2) = h_bits(pv[i][nt][r]);

  float m1f[4][2][4];
#pragma unroll
  for (int n = 0; n < 4; ++n) {
    f32x4 acc[2] = {z4, z4};
#pragma unroll
    for (int kb = 0; kb < 2; ++kb) {
      h16x4 a = *(const h16x4*)(p_lds + (n * 64 + lrow + p) * 80 + kb * 32 + q * 8);
#pragma unroll
      for (int nt = 0; nt < 2; ++nt)
        acc[nt] = MFMA16(a, ldb(We1T, (n * 32 + nt * 16 + p) * 32 + kb * 16 + q * 4), acc[nt]);
    }
#pragma unroll
    for (int nt = 0; nt < 2; ++nt) {
      float bias = be1[n * 32 + nt * 16 + p];
#pragma unroll
      for (int r = 0; r < 4; ++r) m1f[n][nt][r] = fmaxf(acc[nt][r] + bias, 0.f);
    }
  }

  // ---- combine 2: prev2 = einsum(a1, m1) ----
#pragma unroll
  for (int i = 0; i < 4; ++i)
#pragma unroll
    for (int nt = 0; nt < 2; ++nt)
#pragma unroll
      for (int r = 0; r < 4; ++r) pv[i][nt][r] = 0.f;
#pragma unroll
  for (int r = 0; r < 4; ++r) {
#pragma unroll
    for (int c = 0; c < 16; ++c) {
      float av = __shfl(a1v[r], sbase | c);
      pv[c >> 2][0][r] += av * m1f[c & 3][0][r];
      pv[c >> 2][1][r] += av * m1f[c & 3][1][r];
    }
  }

  // ---- prev2 -> p_lds; E2 + relu + sum over n; store f32 ----
  // (p rows are wave-exclusive, so no second barrier needed)
#pragma unroll
  for (int i = 0; i < 4; ++i)
#pragma unroll
    for (int nt = 0; nt < 2; ++nt)
#pragma unroll
      for (int r = 0; r < 4; ++r)
        *(short*)(p_lds + (i * 64 + lrow + 4 * q + r) * 80 + (nt * 16 + p) * 2) = h_bits(pv[i][nt][r]);

  float of[2][4] = {{0.f, 0.f, 0.f, 0.f}, {0.f, 0.f, 0.f, 0.f}};
#pragma unroll
  for (int n = 0; n < 4; ++n) {
    f32x4 acc[2] = {z4, z4};
#pragma unroll
    for (int kb = 0; kb < 2; ++kb) {
      h16x4 a = *(const h16x4*)(p_lds + (n * 64 + lrow + p) * 80 + kb * 32 + q * 8);
#pragma unroll
      for (int nt = 0; nt < 2; ++nt)
        acc[nt] = MFMA16(a, ldb(We2T, (n * 32 + nt * 16 + p) * 32 + kb * 16 + q * 4), acc[nt]);
    }
#pragma unroll
    for (int nt = 0; nt < 2; ++nt) {
      float bias = be2[n * 32 + nt * 16 + p];
#pragma unroll
      for (int r = 0; r < 4; ++r) of[nt][r] += fmaxf(acc[nt][r] + bias, 0.f);
    }
  }
#pragma unroll
  for (int nt = 0; nt < 2; ++nt)
#pragma unroll
    for (int r = 0; r < 4; ++r) {
      int grow = rowblk + 4 * q + r;
      out[(size_t)grow * 32 + nt * 16 + p] = of[nt][r];
    }
}

extern "C" void kernel_launch(void* const* d_in, const int* in_sizes, int n_in,
                              void* d_out, int out_size, void* d_ws, size_t ws_size,
                              hipStream_t stream) {
  (void)in_sizes; (void)n_in; (void)out_size; (void)ws_size;
  const float* obs  = (const float*)d_in[0];
  const float* task = (const float*)d_in[1];
  const float* Ws1 = (const float*)d_in[2];  const float* bs1 = (const float*)d_in[3];
  const float* Ws2 = (const float*)d_in[4];  const float* bs2 = (const float*)d_in[5];
  const float* Wt  = (const float*)d_in[6];  const float* bt  = (const float*)d_in[7];
  const float* Wa0 = (const float*)d_in[8];  const float* ba0 = (const float*)d_in[9];
  const float* Wa1 = (const float*)d_in[10]; const float* ba1 = (const float*)d_in[11];
  const float* Wc0 = (const float*)d_in[12]; const float* bc0 = (const float*)d_in[13];
  // d_in[14]=Wc1, d_in[15]=bc1: dead code in the reference (result unused)
  const float* We0 = (const float*)d_in[16]; const float* be0 = (const float*)d_in[17];
  const float* We1 = (const float*)d_in[18]; const float* be1 = (const float*)d_in[19];
  const float* We2 = (const float*)d_in[20]; const float* be2 = (const float*)d_in[21];

  short* wsh   = (short*)d_ws;
  float* biasf = (float*)((char*)d_ws + 129040);

  sm_convert_v5<<<dim3(255), dim3(256), 0, stream>>>(
      Ws1, Ws2, Wt, Wa0, Wa1, Wc0, We0, We1, We2,
      bs1, bs2, bt, ba0, ba1, bc0, be0, be1, be2,
      wsh, biasf);
  sm_fused_v5<<<dim3(1024), dim3(256), 0, stream>>>(
      obs, task, wsh, biasf, (float*)d_out);
}